// Round 13
// baseline (2876.913 us; speedup 1.0000x reference)
//
#include <hip/hip_runtime.h>

#define HID     1024
#define TSTEPS  19
#define INDIM   17
#define XSTRIDE (TSTEPS * INDIM)

typedef unsigned short u16;
typedef unsigned int   u32;
typedef __attribute__((ext_vector_type(8))) _Float16 f16x8;  // 8 fp16 = 4 VGPRs
typedef __attribute__((ext_vector_type(4))) float f32x4;

__device__ __forceinline__ u16 f2h(float f) {  // fp32 -> fp16 RNE
    union { _Float16 h; u16 u; } v; v.h = (_Float16)f; return v.u;
}
__device__ __forceinline__ float h2f(u16 x) {
    union { _Float16 h; u16 u; } v; v.u = x; return (float)v.h;
}
__device__ __forceinline__ float sigm(float x) {
    x = fminf(fmaxf(x, -30.f), 30.f);
    return 1.f / (1.f + __expf(-x));
}
__device__ __forceinline__ float tanhr(float x) {
    x = fminf(fmaxf(x, -15.f), 15.f);
    float e = __expf(-2.f * x);
    return (1.f - e) / (1.f + e);
}

// Async global->LDS, 16B per lane: HW writes wave-uniform LDS base + lane*16.
__device__ __forceinline__ void gload_lds16(const u16* g, u16* l) {
    __builtin_amdgcn_global_load_lds(
        (const __attribute__((address_space(1))) u32*)g,
        (__attribute__((address_space(3))) u32*)l, 16, 0, 0);
}

// fp32 -> fp16 hi split (weights; no lo needed on the single-term path).
__global__ __launch_bounds__(256) void split_kernel(
    const float* __restrict__ src, u16* __restrict__ hi, int n4)
{
    int i = blockIdx.x * blockDim.x + threadIdx.x;
    if (i >= n4) return;
    float4 v = ((const float4*)src)[i];
    ushort4 h;
    h.x = f2h(v.x); h.y = f2h(v.y); h.z = f2h(v.z); h.w = f2h(v.w);
    ((ushort4*)hi)[i] = h;
}

// Pre-pack x into standard BK=64 GEMM rows: xpack[(t*4096+b)*64 + k] =
// [xhi(17) | xlo(17) | xhi(17) | 0...] -- the 3-term fp16 split of x[b,t,:]
// as one K=64 stage. Done ONCE; replaces the per-phase scalar x staging.
__global__ __launch_bounds__(256) void pack_x_kernel(
    const float* __restrict__ x, u16* __restrict__ xpack)
{
    const int i = blockIdx.x * blockDim.x + threadIdx.x;  // i = t*4096 + b
    if (i >= TSTEPS * 4096) return;
    const int t = i >> 12, b = i & 4095;
    const float* src = x + (size_t)b * XSTRIDE + (size_t)t * INDIM;
    u16 row[64];
#pragma unroll
    for (int k = 0; k < INDIM; ++k) {
        const float v = src[k];
        const u16 hi = f2h(v);
        row[k] = hi;
        row[INDIM + k] = f2h(v - h2f(hi));   // lo
        row[2 * INDIM + k] = hi;
    }
#pragma unroll
    for (int k = 3 * INDIM; k < 64; ++k) row[k] = 0;
    uint4* dst = (uint4*)(xpack + (size_t)i * 64);
#pragma unroll
    for (int q = 0; q < 8; ++q) dst[q] = ((const uint4*)row)[q];
}

// Pre-pack W_ih1 rows to match: wxpack[n*64 + k] = [Whi | Whi | Wlo | 0].
__global__ __launch_bounds__(256) void pack_wx_kernel(
    const float* __restrict__ W, u16* __restrict__ wxpack)
{
    const int n = blockIdx.x * blockDim.x + threadIdx.x;
    if (n >= 4 * HID) return;
    const float* src = W + (size_t)n * INDIM;
    u16 row[64];
#pragma unroll
    for (int k = 0; k < INDIM; ++k) {
        const float v = src[k];
        const u16 hi = f2h(v);
        row[k] = hi;
        row[INDIM + k] = hi;
        row[2 * INDIM + k] = f2h(v - h2f(hi));  // lo
    }
#pragma unroll
    for (int k = 3 * INDIM; k < 64; ++k) row[k] = 0;
    uint4* dst = (uint4*)(wxpack + (size_t)n * 64);
#pragma unroll
    for (int q = 0; q < 8; ++q) dst[q] = ((const uint4*)row)[q];
}

// Fused GEMM + LSTM cell body -- 256x128 tile, 4 waves (r12 structure).
// Each wave keeps the r5-proven per-wave shape (64 rows x 128 vcols, 4x8
// acc, 16x16x32 fp16 MFMA); the B-tile (weights, 128 rows x 64k) is shared
// by 4 waves. Per stage per wave: 8 A-staging + 4 B-staging gload_lds16.
// r13: cell state c is stored fp16 (read h2f / write f2h in the epilogue);
// per-step quantization ~|c|*2^-11 -> ~6e-4 into h, well under threshold.
__device__ __forceinline__ void gate_body(
    u16* lA, u16* lB, int rb, int u0,
    const u16* __restrict__ a0, const u16* __restrict__ w0,
    const u16* __restrict__ a1, const u16* __restrict__ w1,
    const u16* __restrict__ xp, const u16* __restrict__ wxp,
    const float* __restrict__ bi, const float* __restrict__ bh,
    u16* __restrict__ cbuf, u16* __restrict__ outh,
    int first, int nsrc)
{
    const int tid  = threadIdx.x;
    const int wave = tid >> 6;    // 0..3
    const int lane = tid & 63;
    const int col  = lane & 15;   // MFMA A/B m|n index; C/D col
    const int quad = lane >> 4;   // MFMA k-group; C/D row group

    const int lr = lane >> 3;         // staging row-in-group-of-8
    const int ck = (lane & 7) ^ lr;   // xor-swizzled global chunk to fetch

    f32x4 acc[4][8];
    const f32x4 fzero = {0.f, 0.f, 0.f, 0.f};
#pragma unroll
    for (int i = 0; i < 4; ++i)
#pragma unroll
        for (int j = 0; j < 8; ++j) acc[i][j] = fzero;

    const int nst = nsrc << 4;                  // 16 stages per stride-HID pair
    const int ntot = nst + (xp ? 1 : 0);        // + one packed x stage
    for (int s = 0; s < ntot; ++s) {
        const bool isx = (s >= nst);
        const u16* Asrc = isx ? xp  : ((s < 16) ? a0 : a1);
        const u16* Wsrc = isx ? wxp : ((s < 16) ? w0 : w1);
        const int k0 = isx ? 0 : (s & 15) * 64;
        const int st = isx ? 64 : HID;          // row stride (elements)

        __syncthreads();  // previous stage's (or previous body's) reads done
#pragma unroll
        for (int i = 0; i < 8; ++i) {   // A: rows of this wave's 64-row slab
            const int rbase = wave * 64 + i * 8;
            const int r = rbase + lr;
            const u16* gp = Asrc + (size_t)(rb + r) * st + k0 + ck * 8;
            gload_lds16(gp, lA + rbase * 64);   // lane lands at +lane*16B
        }
#pragma unroll
        for (int i = 0; i < 4; ++i) {   // B: this wave's quarter of 128 rows
            const int vbase = wave * 32 + i * 8;
            const int v = vbase + lr;
            const int n = ((v >> 5) << 10) + u0 + (v & 31);  // gate*1024 + u
            const u16* gp = Wsrc + (size_t)n * st + k0 + ck * 8;
            gload_lds16(gp, lB + vbase * 64);
        }
        __syncthreads();  // staging visible (barrier drains vmcnt)

#pragma unroll
        for (int ks = 0; ks < 2; ++ks) {
            const int p = ((ks << 2) + quad) ^ (col & 7);  // swizzled chunk
            f16x8 av[4], bv[8];
#pragma unroll
            for (int rf = 0; rf < 4; ++rf)
                av[rf] = *(const f16x8*)(lA + (wave * 64 + rf * 16 + col) * 64 + p * 8);
#pragma unroll
            for (int cf = 0; cf < 8; ++cf)
                bv[cf] = *(const f16x8*)(lB + (cf * 16 + col) * 64 + p * 8);
#pragma unroll
            for (int rf = 0; rf < 4; ++rf)
#pragma unroll
                for (int cf = 0; cf < 8; ++cf)
                    acc[rf][cf] = __builtin_amdgcn_mfma_f32_16x16x32_f16(
                        av[rf], bv[cf], acc[rf][cf], 0, 0, 0);
        }
    }

    // Epilogue: per-lane LSTM cell. C/D layout: col=lane&15, row=quad*4+reg.
    // Gates of unit u = u0 + s2*16 + col live at cf = {s2, 2+s2, 4+s2, 6+s2}.
#pragma unroll
    for (int s2 = 0; s2 < 2; ++s2) {
        const int u = u0 + s2 * 16 + col;
        const float bI = bi[u]           + bh[u];
        const float bF = bi[HID + u]     + bh[HID + u];
        const float bG = bi[2 * HID + u] + bh[2 * HID + u];
        const float bO = bi[3 * HID + u] + bh[3 * HID + u];
#pragma unroll
        for (int rf = 0; rf < 4; ++rf) {
#pragma unroll
            for (int rr = 0; rr < 4; ++rr) {
                const int brow = rb + wave * 64 + rf * 16 + quad * 4 + rr;
                const size_t idx = (size_t)brow * HID + u;
                const float iv = sigm(acc[rf][0 + s2][rr] + bI);
                const float fv = sigm(acc[rf][2 + s2][rr] + bF);
                const float gv = tanhr(acc[rf][4 + s2][rr] + bG);
                const float ov = sigm(acc[rf][6 + s2][rr] + bO);
                const float cold = first ? 0.f : h2f(cbuf[idx]);
                const float cn = fv * cold + iv * gv;
                const float hn = ov * tanhr(cn);
                cbuf[idx] = f2h(cn);
                outh[idx] = f2h(hn);
            }
        }
    }
}

// out[b, t, :] = h2[b,:] @ W_lin^T + b_lin in fp32 (h2 fp16).
// 8 rows per 256-thr block: each wave 2 rows; 32 k-slices of 32 units;
// xor-shuffle reduce over the 32 slices; lanes q<17 write the outputs.
__device__ __forceinline__ void out_body8(int oid,
    const u16* __restrict__ h2h,
    const float* __restrict__ Wlin, const float* __restrict__ blin,
    float* __restrict__ out, int t)
{
    const int tid = threadIdx.x;
    const int wave = tid >> 6, lane = tid & 63;
    const int r = lane >> 5, q = lane & 31;
    const int b = oid * 8 + wave * 2 + r;
    const u16* hh = h2h + (size_t)b * HID;
    float acc[INDIM];
#pragma unroll
    for (int j = 0; j < INDIM; ++j) acc[j] = 0.f;
#pragma unroll 2
    for (int it = 0; it < 8; ++it) {
        const int u = q * 32 + it * 4;
        const ushort4 a = *(const ushort4*)(hh + u);
        const float h0 = h2f(a.x), h1 = h2f(a.y), h2 = h2f(a.z), h3 = h2f(a.w);
#pragma unroll
        for (int j = 0; j < INDIM; ++j) {
            const float4 w = *(const float4*)(Wlin + j * HID + u);
            acc[j] += h0 * w.x + h1 * w.y + h2 * w.z + h3 * w.w;
        }
    }
#pragma unroll
    for (int j = 0; j < INDIM; ++j) {   // reduce across the 32 q-slices
        float v = acc[j];
        v += __shfl_xor(v, 1);
        v += __shfl_xor(v, 2);
        v += __shfl_xor(v, 4);
        v += __shfl_xor(v, 8);
        v += __shfl_xor(v, 16);
        acc[j] = v;
    }
    const size_t ob = (size_t)b * XSTRIDE + (size_t)t * INDIM;
    float mine = acc[0];
#pragma unroll
    for (int j = 1; j < INDIM; ++j) if (q == j) mine = acc[j];
    if (q < INDIM) out[ob + q] = mine + blin[q];
}

// Fused pipeline step C(s) = { L2(s-1) + L1(s) + OUT(s-2) }, grid EXACTLY
// 512 blocks x 256 thr (2 blocks/CU at 48KB LDS -> 1.0 scheduling rounds).
// Each block owns a 256-row x 32-unit tile; both gate bodies then 8 rows of
// the output linear. XCD-pinned u0 (perf heuristic only). Buffer schedule =
// r8/r10/r11/r12-verified 4-deep slab rotation.
__global__ __launch_bounds__(256, 2) void step_kernel(
    int doA, int doB,
    // role A: layer 2 of step s-1
    const u16* __restrict__ Aa0, const u16* __restrict__ Aw0,
    const u16* __restrict__ Aa1, const u16* __restrict__ Aw1,
    const float* __restrict__ Abi, const float* __restrict__ Abh,
    u16* __restrict__ Acbuf, u16* __restrict__ Aouth, int Afirst, int Ansrc,
    // role B: layer 1 of step s (x via pre-packed stride-64 pair)
    const u16* __restrict__ Ba0, const u16* __restrict__ Bw0,
    const u16* __restrict__ Bxp, const u16* __restrict__ Bwxp,
    const float* __restrict__ Bbi, const float* __restrict__ Bbh,
    u16* __restrict__ Bcbuf, u16* __restrict__ Bouth, int Bfirst, int Bnsrc,
    // role O: output linear of step s-2 (Ot < 0 => skip)
    const u16* __restrict__ Oh2, const float* __restrict__ Wlin,
    const float* __restrict__ blin, float* __restrict__ outp, int Ot)
{
    __shared__ u16 lA[256 * 64];   // 32 KB: 256 batch rows x BK=64
    __shared__ u16 lB[128 * 64];   // 16 KB: 128 weight rows x BK=64
    const int bid = blockIdx.x;
    const int rb  = (bid >> 5) * 256;                        // batch-row block
    const int u0  = ((bid & 7) * 4 + ((bid >> 3) & 3)) * 32; // XCD-pinned tile
    if (doA)
        gate_body(lA, lB, rb, u0, Aa0, Aw0, Aa1, Aw1, nullptr, nullptr,
                  Abi, Abh, Acbuf, Aouth, Afirst, Ansrc);
    if (doB)
        gate_body(lA, lB, rb, u0, Ba0, Bw0, nullptr, nullptr, Bxp, Bwxp,
                  Bbi, Bbh, Bcbuf, Bouth, Bfirst, Bnsrc);
    if (Ot >= 0)
        out_body8(bid, Oh2, Wlin, blin, outp, Ot);
}

extern "C" void kernel_launch(void* const* d_in, const int* in_sizes, int n_in,
                              void* d_out, int out_size, void* d_ws, size_t ws_size,
                              hipStream_t stream)
{
    const float* x     = (const float*)d_in[0];
    const float* W_ih1 = (const float*)d_in[1];
    const float* W_hh1 = (const float*)d_in[2];
    const float* b_ih1 = (const float*)d_in[3];
    const float* b_hh1 = (const float*)d_in[4];
    const float* W_ih2 = (const float*)d_in[5];
    const float* W_hh2 = (const float*)d_in[6];
    const float* b_ih2 = (const float*)d_in[7];
    const float* b_hh2 = (const float*)d_in[8];
    const float* W_lin = (const float*)d_in[9];
    const float* b_lin = (const float*)d_in[10];
    float* out = (float*)d_out;
    char* ws = (char*)d_ws;
    const size_t MB = (size_t)1 << 20;

    // Workspace (~131 MB; no memset -- first=1 skips all reads of
    // uninitialized state at t=0). c1/c2 now fp16 (8 MB each; same base
    // offsets as r12 to keep the layout diff minimal). h1/h2: FOUR 8MB fp16
    // slabs each (t&3).
    u16* c1 = (u16*)(ws);                 // 8 MB used (4096x1024 fp16)
    u16* c2 = (u16*)(ws + 16 * MB);       // 8 MB used
    u16* h1[4] = { (u16*)(ws + 32 * MB), (u16*)(ws + 40 * MB),
                   (u16*)(ws + 48 * MB), (u16*)(ws + 56 * MB) };
    u16* h2[4] = { (u16*)(ws + 64 * MB), (u16*)(ws + 72 * MB),
                   (u16*)(ws + 80 * MB), (u16*)(ws + 88 * MB) };
    u16* w1h    = (u16*)(ws + 96 * MB);   // 8 MB each (4H x H fp16)
    u16* w2ih   = (u16*)(ws + 104 * MB);
    u16* w2hh   = (u16*)(ws + 112 * MB);
    u16* xpack  = (u16*)(ws + 120 * MB);  // 19*4096*64 fp16 = 9.97 MB
    u16* wxpack = (u16*)(ws + 130 * MB);  // 4096*64 fp16 = 0.5 MB

    // Prolog: weight fp16 splits + x / W_ih1 pre-pack (once per call).
    const int nW = 4 * HID * HID / 4;        // 1048576 float4s
    split_kernel<<<(nW + 255) / 256, 256, 0, stream>>>(W_hh1, w1h,  nW);
    split_kernel<<<(nW + 255) / 256, 256, 0, stream>>>(W_ih2, w2ih, nW);
    split_kernel<<<(nW + 255) / 256, 256, 0, stream>>>(W_hh2, w2hh, nW);
    pack_x_kernel<<<(TSTEPS * 4096 + 255) / 256, 256, 0, stream>>>(x, xpack);
    pack_wx_kernel<<<(4 * HID + 255) / 256, 256, 0, stream>>>(W_ih1, wxpack);

    // Software pipeline: C(s) = { L2(s-1) + L1(s) + OUT(s-2) }, s=0..TSTEPS+1.
    // Slabs: L1(t) reads h1[(t+3)&3], writes h1[t&3]; L2(t) reads h1[t&3],
    // h2[(t+3)&3], writes h2[t&3]; OUT(t) reads h2[t&3]. Intra-launch sets
    // disjoint; RAW >= 1 launch, WAR >= 3 launches (r8/r10/r11/r12-verified).
    for (int s = 0; s <= TSTEPS + 1; ++s) {
        const int ta = s - 1, tb = s, to = s - 2;
        const int doA = (s >= 1 && s <= TSTEPS) ? 1 : 0;
        const int doB = (s <= TSTEPS - 1) ? 1 : 0;
        step_kernel<<<512, 256, 0, stream>>>(
            doA, doB,
            // A: L2(ta) = h1[ta&3]@w2ih + h2[(ta+3)&3]@w2hh -> h2[ta&3]
            h1[ta & 3], w2ih, h2[(ta + 3) & 3], w2hh, b_ih2, b_hh2,
            c2, h2[ta & 3], (ta == 0) ? 1 : 0, (ta == 0) ? 1 : 2,
            // B: L1(tb) = xpack(tb) + h1[(tb+3)&3]@w1h -> h1[tb&3]
            h1[(tb + 3) & 3], w1h,
            xpack + (size_t)(tb < 0 ? 0 : tb) * 4096 * 64, wxpack,
            b_ih1, b_hh1,
            c1, h1[tb & 3], (tb == 0) ? 1 : 0, (tb == 0) ? 0 : 1,
            // O: OUT(to) reads h2[to&3] (skipped when to < 0)
            h2[to & 3], W_lin, b_lin, out, to);
    }
    (void)in_sizes; (void)n_in; (void)out_size; (void)ws_size;
}

// Round 14
// 2778.835 us; speedup vs baseline: 1.0353x; 1.0353x over previous
//
#include <hip/hip_runtime.h>

#define HID     1024
#define TSTEPS  19
#define INDIM   17
#define XSTRIDE (TSTEPS * INDIM)

typedef unsigned short u16;
typedef unsigned int   u32;
typedef __attribute__((ext_vector_type(8))) _Float16 f16x8;  // 8 fp16 = 4 VGPRs
typedef __attribute__((ext_vector_type(4))) float f32x4;

__device__ __forceinline__ u16 f2h(float f) {  // fp32 -> fp16 RNE
    union { _Float16 h; u16 u; } v; v.h = (_Float16)f; return v.u;
}
__device__ __forceinline__ float h2f(u16 x) {
    union { _Float16 h; u16 u; } v; v.u = x; return (float)v.h;
}
__device__ __forceinline__ float sigm(float x) {
    x = fminf(fmaxf(x, -30.f), 30.f);
    return 1.f / (1.f + __expf(-x));
}
__device__ __forceinline__ float tanhr(float x) {
    x = fminf(fmaxf(x, -15.f), 15.f);
    float e = __expf(-2.f * x);
    return (1.f - e) / (1.f + e);
}

// Async global->LDS, 16B per lane: HW writes wave-uniform LDS base + lane*16.
__device__ __forceinline__ void gload_lds16(const u16* g, u16* l) {
    __builtin_amdgcn_global_load_lds(
        (const __attribute__((address_space(1))) u32*)g,
        (__attribute__((address_space(3))) u32*)l, 16, 0, 0);
}

// fp32 -> fp16 hi split (weights; no lo needed on the single-term path).
__global__ __launch_bounds__(256) void split_kernel(
    const float* __restrict__ src, u16* __restrict__ hi, int n4)
{
    int i = blockIdx.x * blockDim.x + threadIdx.x;
    if (i >= n4) return;
    float4 v = ((const float4*)src)[i];
    ushort4 h;
    h.x = f2h(v.x); h.y = f2h(v.y); h.z = f2h(v.z); h.w = f2h(v.w);
    ((ushort4*)hi)[i] = h;
}

// Pre-pack x into standard BK=64 GEMM rows: xpack[(t*4096+b)*64 + k] =
// [xhi(17) | xlo(17) | xhi(17) | 0...] -- the 3-term fp16 split of x[b,t,:]
// as one K=64 stage. Done ONCE; replaces per-phase scalar x staging.
__global__ __launch_bounds__(256) void pack_x_kernel(
    const float* __restrict__ x, u16* __restrict__ xpack)
{
    const int i = blockIdx.x * blockDim.x + threadIdx.x;  // i = t*4096 + b
    if (i >= TSTEPS * 4096) return;
    const int t = i >> 12, b = i & 4095;
    const float* src = x + (size_t)b * XSTRIDE + (size_t)t * INDIM;
    u16 row[64];
#pragma unroll
    for (int k = 0; k < INDIM; ++k) {
        const float v = src[k];
        const u16 hi = f2h(v);
        row[k] = hi;
        row[INDIM + k] = f2h(v - h2f(hi));   // lo
        row[2 * INDIM + k] = hi;
    }
#pragma unroll
    for (int k = 3 * INDIM; k < 64; ++k) row[k] = 0;
    uint4* dst = (uint4*)(xpack + (size_t)i * 64);
#pragma unroll
    for (int q = 0; q < 8; ++q) dst[q] = ((const uint4*)row)[q];
}

// Pre-pack W_ih1 rows to match: wxpack[n*64 + k] = [Whi | Whi | Wlo | 0].
__global__ __launch_bounds__(256) void pack_wx_kernel(
    const float* __restrict__ W, u16* __restrict__ wxpack)
{
    const int n = blockIdx.x * blockDim.x + threadIdx.x;
    if (n >= 4 * HID) return;
    const float* src = W + (size_t)n * INDIM;
    u16 row[64];
#pragma unroll
    for (int k = 0; k < INDIM; ++k) {
        const float v = src[k];
        const u16 hi = f2h(v);
        row[k] = hi;
        row[INDIM + k] = hi;
        row[2 * INDIM + k] = f2h(v - h2f(hi));  // lo
    }
#pragma unroll
    for (int k = 3 * INDIM; k < 64; ++k) row[k] = 0;
    uint4* dst = (uint4*)(wxpack + (size_t)n * 64);
#pragma unroll
    for (int q = 0; q < 8; ++q) dst[q] = ((const uint4*)row)[q];
}

// Fused GEMM + LSTM cell body -- 256x128 tile, 4 waves (r12 structure,
// c back to fp32 after r13's fp16-c regression: sub-word c accesses cost
// more in the latency-exposed epilogue than the saved bytes).
__device__ __forceinline__ void gate_body(
    u16* lA, u16* lB, int rb, int u0,
    const u16* __restrict__ a0, const u16* __restrict__ w0,
    const u16* __restrict__ a1, const u16* __restrict__ w1,
    const u16* __restrict__ xp, const u16* __restrict__ wxp,
    const float* __restrict__ bi, const float* __restrict__ bh,
    float* __restrict__ cbuf, u16* __restrict__ outh,
    int first, int nsrc)
{
    const int tid  = threadIdx.x;
    const int wave = tid >> 6;    // 0..3
    const int lane = tid & 63;
    const int col  = lane & 15;   // MFMA A/B m|n index; C/D col
    const int quad = lane >> 4;   // MFMA k-group; C/D row group

    const int lr = lane >> 3;         // staging row-in-group-of-8
    const int ck = (lane & 7) ^ lr;   // xor-swizzled global chunk to fetch

    f32x4 acc[4][8];
    const f32x4 fzero = {0.f, 0.f, 0.f, 0.f};
#pragma unroll
    for (int i = 0; i < 4; ++i)
#pragma unroll
        for (int j = 0; j < 8; ++j) acc[i][j] = fzero;

    const int nst = nsrc << 4;                  // 16 stages per stride-HID pair
    const int ntot = nst + (xp ? 1 : 0);        // + one packed x stage
    for (int s = 0; s < ntot; ++s) {
        const bool isx = (s >= nst);
        const u16* Asrc = isx ? xp  : ((s < 16) ? a0 : a1);
        const u16* Wsrc = isx ? wxp : ((s < 16) ? w0 : w1);
        const int k0 = isx ? 0 : (s & 15) * 64;
        const int st = isx ? 64 : HID;          // row stride (elements)

        __syncthreads();  // previous stage's (or previous body's) reads done
#pragma unroll
        for (int i = 0; i < 8; ++i) {   // A: rows of this wave's 64-row slab
            const int rbase = wave * 64 + i * 8;
            const int r = rbase + lr;
            const u16* gp = Asrc + (size_t)(rb + r) * st + k0 + ck * 8;
            gload_lds16(gp, lA + rbase * 64);   // lane lands at +lane*16B
        }
#pragma unroll
        for (int i = 0; i < 4; ++i) {   // B: this wave's quarter of 128 rows
            const int vbase = wave * 32 + i * 8;
            const int v = vbase + lr;
            const int n = ((v >> 5) << 10) + u0 + (v & 31);  // gate*1024 + u
            const u16* gp = Wsrc + (size_t)n * st + k0 + ck * 8;
            gload_lds16(gp, lB + vbase * 64);
        }
        __syncthreads();  // staging visible (barrier drains vmcnt)

#pragma unroll
        for (int ks = 0; ks < 2; ++ks) {
            const int p = ((ks << 2) + quad) ^ (col & 7);  // swizzled chunk
            f16x8 av[4], bv[8];
#pragma unroll
            for (int rf = 0; rf < 4; ++rf)
                av[rf] = *(const f16x8*)(lA + (wave * 64 + rf * 16 + col) * 64 + p * 8);
#pragma unroll
            for (int cf = 0; cf < 8; ++cf)
                bv[cf] = *(const f16x8*)(lB + (cf * 16 + col) * 64 + p * 8);
#pragma unroll
            for (int rf = 0; rf < 4; ++rf)
#pragma unroll
                for (int cf = 0; cf < 8; ++cf)
                    acc[rf][cf] = __builtin_amdgcn_mfma_f32_16x16x32_f16(
                        av[rf], bv[cf], acc[rf][cf], 0, 0, 0);
        }
    }

    // Epilogue: per-lane LSTM cell. C/D layout: col=lane&15, row=quad*4+reg.
    // Gates of unit u = u0 + s2*16 + col live at cf = {s2, 2+s2, 4+s2, 6+s2}.
#pragma unroll
    for (int s2 = 0; s2 < 2; ++s2) {
        const int u = u0 + s2 * 16 + col;
        const float bI = bi[u]           + bh[u];
        const float bF = bi[HID + u]     + bh[HID + u];
        const float bG = bi[2 * HID + u] + bh[2 * HID + u];
        const float bO = bi[3 * HID + u] + bh[3 * HID + u];
#pragma unroll
        for (int rf = 0; rf < 4; ++rf) {
#pragma unroll
            for (int rr = 0; rr < 4; ++rr) {
                const int brow = rb + wave * 64 + rf * 16 + quad * 4 + rr;
                const size_t idx = (size_t)brow * HID + u;
                const float iv = sigm(acc[rf][0 + s2][rr] + bI);
                const float fv = sigm(acc[rf][2 + s2][rr] + bF);
                const float gv = tanhr(acc[rf][4 + s2][rr] + bG);
                const float ov = sigm(acc[rf][6 + s2][rr] + bO);
                const float cold = first ? 0.f : cbuf[idx];
                const float cn = fv * cold + iv * gv;
                const float hn = ov * tanhr(cn);
                cbuf[idx] = cn;
                outh[idx] = f2h(hn);
            }
        }
    }
}

// out[b, t, :] = h2[b,:] @ W_lin^T + b_lin in fp32 (h2 fp16).
// 8 rows per 256-thr block: each wave 2 rows; 32 k-slices of 32 units;
// xor-shuffle reduce over the 32 slices; lanes q<17 write the outputs.
__device__ __forceinline__ void out_body8(int oid,
    const u16* __restrict__ h2h,
    const float* __restrict__ Wlin, const float* __restrict__ blin,
    float* __restrict__ out, int t)
{
    const int tid = threadIdx.x;
    const int wave = tid >> 6, lane = tid & 63;
    const int r = lane >> 5, q = lane & 31;
    const int b = oid * 8 + wave * 2 + r;
    const u16* hh = h2h + (size_t)b * HID;
    float acc[INDIM];
#pragma unroll
    for (int j = 0; j < INDIM; ++j) acc[j] = 0.f;
#pragma unroll 2
    for (int it = 0; it < 8; ++it) {
        const int u = q * 32 + it * 4;
        const ushort4 a = *(const ushort4*)(hh + u);
        const float h0 = h2f(a.x), h1 = h2f(a.y), h2 = h2f(a.z), h3 = h2f(a.w);
#pragma unroll
        for (int j = 0; j < INDIM; ++j) {
            const float4 w = *(const float4*)(Wlin + j * HID + u);
            acc[j] += h0 * w.x + h1 * w.y + h2 * w.z + h3 * w.w;
        }
    }
#pragma unroll
    for (int j = 0; j < INDIM; ++j) {   // reduce across the 32 q-slices
        float v = acc[j];
        v += __shfl_xor(v, 1);
        v += __shfl_xor(v, 2);
        v += __shfl_xor(v, 4);
        v += __shfl_xor(v, 8);
        v += __shfl_xor(v, 16);
        acc[j] = v;
    }
    const size_t ob = (size_t)b * XSTRIDE + (size_t)t * INDIM;
    float mine = acc[0];
#pragma unroll
    for (int j = 1; j < INDIM; ++j) if (q == j) mine = acc[j];
    if (q < INDIM) out[ob + q] = mine + blin[q];
}

// Fused pipeline step C(s) = { L2(s-1) + L1(s) + OUT(s-2) }, grid EXACTLY
// 512 blocks x 256 thr (2 blocks/CU at 48KB LDS -> 1.0 scheduling rounds).
// r14: role-order STAGGER by block parity -- odd blocks run B(L1) first,
// even blocks A(L2) first, so a CU's two resident blocks are mostly in
// different roles: one block's MFMA window overlaps the other's staging/
// barrier drains (m114 co-scheduling). Value-identical per element (roles
// touch disjoint buffers; LDS reuse protected by per-stage syncthreads).
// XCD-pinned u0 (perf heuristic only). Buffer schedule = verified 4-deep
// slab rotation (r8/r10/r11/r12).
__global__ __launch_bounds__(256, 2) void step_kernel(
    int doA, int doB,
    // role A: layer 2 of step s-1
    const u16* __restrict__ Aa0, const u16* __restrict__ Aw0,
    const u16* __restrict__ Aa1, const u16* __restrict__ Aw1,
    const float* __restrict__ Abi, const float* __restrict__ Abh,
    float* __restrict__ Acbuf, u16* __restrict__ Aouth, int Afirst, int Ansrc,
    // role B: layer 1 of step s (x via pre-packed stride-64 pair)
    const u16* __restrict__ Ba0, const u16* __restrict__ Bw0,
    const u16* __restrict__ Bxp, const u16* __restrict__ Bwxp,
    const float* __restrict__ Bbi, const float* __restrict__ Bbh,
    float* __restrict__ Bcbuf, u16* __restrict__ Bouth, int Bfirst, int Bnsrc,
    // role O: output linear of step s-2 (Ot < 0 => skip)
    const u16* __restrict__ Oh2, const float* __restrict__ Wlin,
    const float* __restrict__ blin, float* __restrict__ outp, int Ot)
{
    __shared__ u16 lA[256 * 64];   // 32 KB: 256 batch rows x BK=64
    __shared__ u16 lB[128 * 64];   // 16 KB: 128 weight rows x BK=64
    const int bid = blockIdx.x;
    const int rb  = (bid >> 5) * 256;                        // batch-row block
    const int u0  = ((bid & 7) * 4 + ((bid >> 3) & 3)) * 32; // XCD-pinned tile
    const auto runA = [&]() {
        gate_body(lA, lB, rb, u0, Aa0, Aw0, Aa1, Aw1, nullptr, nullptr,
                  Abi, Abh, Acbuf, Aouth, Afirst, Ansrc);
    };
    const auto runB = [&]() {
        gate_body(lA, lB, rb, u0, Ba0, Bw0, nullptr, nullptr, Bxp, Bwxp,
                  Bbi, Bbh, Bcbuf, Bouth, Bfirst, Bnsrc);
    };
    if (bid & 1) { if (doB) runB(); if (doA) runA(); }
    else         { if (doA) runA(); if (doB) runB(); }
    if (Ot >= 0)
        out_body8(bid, Oh2, Wlin, blin, outp, Ot);
}

extern "C" void kernel_launch(void* const* d_in, const int* in_sizes, int n_in,
                              void* d_out, int out_size, void* d_ws, size_t ws_size,
                              hipStream_t stream)
{
    const float* x     = (const float*)d_in[0];
    const float* W_ih1 = (const float*)d_in[1];
    const float* W_hh1 = (const float*)d_in[2];
    const float* b_ih1 = (const float*)d_in[3];
    const float* b_hh1 = (const float*)d_in[4];
    const float* W_ih2 = (const float*)d_in[5];
    const float* W_hh2 = (const float*)d_in[6];
    const float* b_ih2 = (const float*)d_in[7];
    const float* b_hh2 = (const float*)d_in[8];
    const float* W_lin = (const float*)d_in[9];
    const float* b_lin = (const float*)d_in[10];
    float* out = (float*)d_out;
    char* ws = (char*)d_ws;
    const size_t MB = (size_t)1 << 20;

    // Workspace (~131 MB; no memset -- first=1 skips all reads of
    // uninitialized state at t=0). c1/c2 fp32 (r12 layout); h1/h2: FOUR 8MB
    // fp16 slabs each (t&3).
    float* c1 = (float*)(ws);             // 16 MB (4096x1024 fp32)
    float* c2 = (float*)(ws + 16 * MB);   // 16 MB
    u16* h1[4] = { (u16*)(ws + 32 * MB), (u16*)(ws + 40 * MB),
                   (u16*)(ws + 48 * MB), (u16*)(ws + 56 * MB) };
    u16* h2[4] = { (u16*)(ws + 64 * MB), (u16*)(ws + 72 * MB),
                   (u16*)(ws + 80 * MB), (u16*)(ws + 88 * MB) };
    u16* w1h    = (u16*)(ws + 96 * MB);   // 8 MB each (4H x H fp16)
    u16* w2ih   = (u16*)(ws + 104 * MB);
    u16* w2hh   = (u16*)(ws + 112 * MB);
    u16* xpack  = (u16*)(ws + 120 * MB);  // 19*4096*64 fp16 = 9.97 MB
    u16* wxpack = (u16*)(ws + 130 * MB);  // 4096*64 fp16 = 0.5 MB

    // Prolog: weight fp16 splits + x / W_ih1 pre-pack (once per call).
    const int nW = 4 * HID * HID / 4;        // 1048576 float4s
    split_kernel<<<(nW + 255) / 256, 256, 0, stream>>>(W_hh1, w1h,  nW);
    split_kernel<<<(nW + 255) / 256, 256, 0, stream>>>(W_ih2, w2ih, nW);
    split_kernel<<<(nW + 255) / 256, 256, 0, stream>>>(W_hh2, w2hh, nW);
    pack_x_kernel<<<(TSTEPS * 4096 + 255) / 256, 256, 0, stream>>>(x, xpack);
    pack_wx_kernel<<<(4 * HID + 255) / 256, 256, 0, stream>>>(W_ih1, wxpack);

    // Software pipeline: C(s) = { L2(s-1) + L1(s) + OUT(s-2) }, s=0..TSTEPS+1.
    // Slabs: L1(t) reads h1[(t+3)&3], writes h1[t&3]; L2(t) reads h1[t&3],
    // h2[(t+3)&3], writes h2[t&3]; OUT(t) reads h2[t&3]. Intra-launch sets
    // disjoint; RAW >= 1 launch, WAR >= 3 launches (verified r8-r12).
    for (int s = 0; s <= TSTEPS + 1; ++s) {
        const int ta = s - 1, tb = s, to = s - 2;
        const int doA = (s >= 1 && s <= TSTEPS) ? 1 : 0;
        const int doB = (s <= TSTEPS - 1) ? 1 : 0;
        step_kernel<<<512, 256, 0, stream>>>(
            doA, doB,
            // A: L2(ta) = h1[ta&3]@w2ih + h2[(ta+3)&3]@w2hh -> h2[ta&3]
            h1[ta & 3], w2ih, h2[(ta + 3) & 3], w2hh, b_ih2, b_hh2,
            c2, h2[ta & 3], (ta == 0) ? 1 : 0, (ta == 0) ? 1 : 2,
            // B: L1(tb) = xpack(tb) + h1[(tb+3)&3]@w1h -> h1[tb&3]
            h1[(tb + 3) & 3], w1h,
            xpack + (size_t)(tb < 0 ? 0 : tb) * 4096 * 64, wxpack,
            b_ih1, b_hh1,
            c1, h1[tb & 3], (tb == 0) ? 1 : 0, (tb == 0) ? 0 : 1,
            // O: OUT(to) reads h2[to&3] (skipped when to < 0)
            h2[to & 3], W_lin, b_lin, out, to);
    }
    (void)in_sizes; (void)n_in; (void)out_size; (void)ws_size;
}

// Round 15
// 2419.808 us; speedup vs baseline: 1.1889x; 1.1484x over previous
//
#include <hip/hip_runtime.h>

#define HID     1024
#define TSTEPS  19
#define INDIM   17
#define XSTRIDE (TSTEPS * INDIM)

typedef unsigned short u16;
typedef unsigned int   u32;
typedef __attribute__((ext_vector_type(8))) _Float16 f16x8;  // 8 fp16 = 4 VGPRs
typedef __attribute__((ext_vector_type(4))) float f32x4;

__device__ __forceinline__ u16 f2h(float f) {  // fp32 -> fp16 RNE
    union { _Float16 h; u16 u; } v; v.h = (_Float16)f; return v.u;
}
__device__ __forceinline__ float h2f(u16 x) {
    union { _Float16 h; u16 u; } v; v.u = x; return (float)v.h;
}
__device__ __forceinline__ float sigm(float x) {
    x = fminf(fmaxf(x, -30.f), 30.f);
    return 1.f / (1.f + __expf(-x));
}
__device__ __forceinline__ float tanhr(float x) {
    x = fminf(fmaxf(x, -15.f), 15.f);
    float e = __expf(-2.f * x);
    return (1.f - e) / (1.f + e);
}

// Async global->LDS, 16B per lane: HW writes wave-uniform LDS base + lane*16.
__device__ __forceinline__ void gload_lds16(const u16* g, u16* l) {
    __builtin_amdgcn_global_load_lds(
        (const __attribute__((address_space(1))) u32*)g,
        (__attribute__((address_space(3))) u32*)l, 16, 0, 0);
}

// Fused prolog split: fp32 -> fp16 hi for the three big weights + W_lin,
// one launch (r14 used 3 split launches + W_lin stayed fp32 in the O-body).
#define NW4 1048576   // float4s per 4H x H weight
__global__ __launch_bounds__(256) void split4_kernel(
    const float* __restrict__ a, u16* __restrict__ ah,
    const float* __restrict__ b, u16* __restrict__ bh,
    const float* __restrict__ c, u16* __restrict__ ch,
    const float* __restrict__ d, u16* __restrict__ dh, int nd4)
{
    int i = blockIdx.x * blockDim.x + threadIdx.x;
    const float* src; u16* dst; int off;
    if (i < NW4)               { src = a; dst = ah; off = i; }
    else if (i < 2 * NW4)      { src = b; dst = bh; off = i - NW4; }
    else if (i < 3 * NW4)      { src = c; dst = ch; off = i - 2 * NW4; }
    else if (i < 3 * NW4 + nd4){ src = d; dst = dh; off = i - 3 * NW4; }
    else return;
    float4 v = ((const float4*)src)[off];
    ushort4 h;
    h.x = f2h(v.x); h.y = f2h(v.y); h.z = f2h(v.z); h.w = f2h(v.w);
    ((ushort4*)dst)[off] = h;
}

// Pre-pack x into standard BK=64 GEMM rows: xpack[(t*4096+b)*64 + k] =
// [xhi(17) | xlo(17) | xhi(17) | 0...] -- the 3-term fp16 split of x[b,t,:]
// as one K=64 stage. Done ONCE; replaces per-phase scalar x staging.
__global__ __launch_bounds__(256) void pack_x_kernel(
    const float* __restrict__ x, u16* __restrict__ xpack)
{
    const int i = blockIdx.x * blockDim.x + threadIdx.x;  // i = t*4096 + b
    if (i >= TSTEPS * 4096) return;
    const int t = i >> 12, b = i & 4095;
    const float* src = x + (size_t)b * XSTRIDE + (size_t)t * INDIM;
    u16 row[64];
#pragma unroll
    for (int k = 0; k < INDIM; ++k) {
        const float v = src[k];
        const u16 hi = f2h(v);
        row[k] = hi;
        row[INDIM + k] = f2h(v - h2f(hi));   // lo
        row[2 * INDIM + k] = hi;
    }
#pragma unroll
    for (int k = 3 * INDIM; k < 64; ++k) row[k] = 0;
    uint4* dst = (uint4*)(xpack + (size_t)i * 64);
#pragma unroll
    for (int q = 0; q < 8; ++q) dst[q] = ((const uint4*)row)[q];
}

// Pre-pack W_ih1 rows to match: wxpack[n*64 + k] = [Whi | Whi | Wlo | 0].
__global__ __launch_bounds__(256) void pack_wx_kernel(
    const float* __restrict__ W, u16* __restrict__ wxpack)
{
    const int n = blockIdx.x * blockDim.x + threadIdx.x;
    if (n >= 4 * HID) return;
    const float* src = W + (size_t)n * INDIM;
    u16 row[64];
#pragma unroll
    for (int k = 0; k < INDIM; ++k) {
        const float v = src[k];
        const u16 hi = f2h(v);
        row[k] = hi;
        row[INDIM + k] = hi;
        row[2 * INDIM + k] = f2h(v - h2f(hi));  // lo
    }
#pragma unroll
    for (int k = 3 * INDIM; k < 64; ++k) row[k] = 0;
    uint4* dst = (uint4*)(wxpack + (size_t)n * 64);
#pragma unroll
    for (int q = 0; q < 8; ++q) dst[q] = ((const uint4*)row)[q];
}

// Fused GEMM + LSTM cell body -- 256x128 tile, 4 waves (r12 structure,
// c fp32 -- r13's fp16-c regressed: sub-word c accesses cost more in the
// latency-exposed epilogue than the saved bytes).
__device__ __forceinline__ void gate_body(
    u16* lA, u16* lB, int rb, int u0,
    const u16* __restrict__ a0, const u16* __restrict__ w0,
    const u16* __restrict__ a1, const u16* __restrict__ w1,
    const u16* __restrict__ xp, const u16* __restrict__ wxp,
    const float* __restrict__ bi, const float* __restrict__ bh,
    float* __restrict__ cbuf, u16* __restrict__ outh,
    int first, int nsrc)
{
    const int tid  = threadIdx.x;
    const int wave = tid >> 6;    // 0..3
    const int lane = tid & 63;
    const int col  = lane & 15;   // MFMA A/B m|n index; C/D col
    const int quad = lane >> 4;   // MFMA k-group; C/D row group

    const int lr = lane >> 3;         // staging row-in-group-of-8
    const int ck = (lane & 7) ^ lr;   // xor-swizzled global chunk to fetch

    f32x4 acc[4][8];
    const f32x4 fzero = {0.f, 0.f, 0.f, 0.f};
#pragma unroll
    for (int i = 0; i < 4; ++i)
#pragma unroll
        for (int j = 0; j < 8; ++j) acc[i][j] = fzero;

    const int nst = nsrc << 4;                  // 16 stages per stride-HID pair
    const int ntot = nst + (xp ? 1 : 0);        // + one packed x stage
    for (int s = 0; s < ntot; ++s) {
        const bool isx = (s >= nst);
        const u16* Asrc = isx ? xp  : ((s < 16) ? a0 : a1);
        const u16* Wsrc = isx ? wxp : ((s < 16) ? w0 : w1);
        const int k0 = isx ? 0 : (s & 15) * 64;
        const int st = isx ? 64 : HID;          // row stride (elements)

        __syncthreads();  // previous stage's (or previous body's) reads done
#pragma unroll
        for (int i = 0; i < 8; ++i) {   // A: rows of this wave's 64-row slab
            const int rbase = wave * 64 + i * 8;
            const int r = rbase + lr;
            const u16* gp = Asrc + (size_t)(rb + r) * st + k0 + ck * 8;
            gload_lds16(gp, lA + rbase * 64);   // lane lands at +lane*16B
        }
#pragma unroll
        for (int i = 0; i < 4; ++i) {   // B: this wave's quarter of 128 rows
            const int vbase = wave * 32 + i * 8;
            const int v = vbase + lr;
            const int n = ((v >> 5) << 10) + u0 + (v & 31);  // gate*1024 + u
            const u16* gp = Wsrc + (size_t)n * st + k0 + ck * 8;
            gload_lds16(gp, lB + vbase * 64);
        }
        __syncthreads();  // staging visible (barrier drains vmcnt)

#pragma unroll
        for (int ks = 0; ks < 2; ++ks) {
            const int p = ((ks << 2) + quad) ^ (col & 7);  // swizzled chunk
            f16x8 av[4], bv[8];
#pragma unroll
            for (int rf = 0; rf < 4; ++rf)
                av[rf] = *(const f16x8*)(lA + (wave * 64 + rf * 16 + col) * 64 + p * 8);
#pragma unroll
            for (int cf = 0; cf < 8; ++cf)
                bv[cf] = *(const f16x8*)(lB + (cf * 16 + col) * 64 + p * 8);
#pragma unroll
            for (int rf = 0; rf < 4; ++rf)
#pragma unroll
                for (int cf = 0; cf < 8; ++cf)
                    acc[rf][cf] = __builtin_amdgcn_mfma_f32_16x16x32_f16(
                        av[rf], bv[cf], acc[rf][cf], 0, 0, 0);
        }
    }

    // Epilogue: per-lane LSTM cell. C/D layout: col=lane&15, row=quad*4+reg.
    // Gates of unit u = u0 + s2*16 + col live at cf = {s2, 2+s2, 4+s2, 6+s2}.
#pragma unroll
    for (int s2 = 0; s2 < 2; ++s2) {
        const int u = u0 + s2 * 16 + col;
        const float bI = bi[u]           + bh[u];
        const float bF = bi[HID + u]     + bh[HID + u];
        const float bG = bi[2 * HID + u] + bh[2 * HID + u];
        const float bO = bi[3 * HID + u] + bh[3 * HID + u];
#pragma unroll
        for (int rf = 0; rf < 4; ++rf) {
#pragma unroll
            for (int rr = 0; rr < 4; ++rr) {
                const int brow = rb + wave * 64 + rf * 16 + quad * 4 + rr;
                const size_t idx = (size_t)brow * HID + u;
                const float iv = sigm(acc[rf][0 + s2][rr] + bI);
                const float fv = sigm(acc[rf][2 + s2][rr] + bF);
                const float gv = tanhr(acc[rf][4 + s2][rr] + bG);
                const float ov = sigm(acc[rf][6 + s2][rr] + bO);
                const float cold = first ? 0.f : cbuf[idx];
                const float cn = fv * cold + iv * gv;
                const float hn = ov * tanhr(cn);
                cbuf[idx] = cn;
                outh[idx] = f2h(hn);
            }
        }
    }
}

// out[b, t, :] = h2[b,:] @ W_lin^T + b_lin (h2 fp16, W_lin pre-split fp16 --
// 34 KB, L1-resident vs 68 KB fp32 L2 stream; fp32 accumulate, err ~3e-4).
// 8 rows per 256-thr block: each wave 2 rows; 32 k-slices of 32 units;
// xor-shuffle reduce over the 32 slices; lanes q<17 write the outputs.
__device__ __forceinline__ void out_body8(int oid,
    const u16* __restrict__ h2h,
    const u16* __restrict__ Wlin, const float* __restrict__ blin,
    float* __restrict__ out, int t)
{
    const int tid = threadIdx.x;
    const int wave = tid >> 6, lane = tid & 63;
    const int r = lane >> 5, q = lane & 31;
    const int b = oid * 8 + wave * 2 + r;
    const u16* hh = h2h + (size_t)b * HID;
    float acc[INDIM];
#pragma unroll
    for (int j = 0; j < INDIM; ++j) acc[j] = 0.f;
#pragma unroll 2
    for (int it = 0; it < 8; ++it) {
        const int u = q * 32 + it * 4;
        const ushort4 a = *(const ushort4*)(hh + u);
        const float h0 = h2f(a.x), h1 = h2f(a.y), h2 = h2f(a.z), h3 = h2f(a.w);
#pragma unroll
        for (int j = 0; j < INDIM; ++j) {
            const ushort4 w = *(const ushort4*)(Wlin + j * HID + u);
            acc[j] += h0 * h2f(w.x) + h1 * h2f(w.y)
                    + h2 * h2f(w.z) + h3 * h2f(w.w);
        }
    }
#pragma unroll
    for (int j = 0; j < INDIM; ++j) {   // reduce across the 32 q-slices
        float v = acc[j];
        v += __shfl_xor(v, 1);
        v += __shfl_xor(v, 2);
        v += __shfl_xor(v, 4);
        v += __shfl_xor(v, 8);
        v += __shfl_xor(v, 16);
        acc[j] = v;
    }
    const size_t ob = (size_t)b * XSTRIDE + (size_t)t * INDIM;
    float mine = acc[0];
#pragma unroll
    for (int j = 1; j < INDIM; ++j) if (q == j) mine = acc[j];
    if (q < INDIM) out[ob + q] = mine + blin[q];
}

// Fused pipeline step C(s) = { L2(s-1) + L1(s) + OUT(s-2) }, grid EXACTLY
// 512 blocks x 256 thr (2 blocks/CU at 48KB LDS -> 1.0 scheduling rounds).
// Role-order STAGGER by block parity (r14, +2%): odd blocks run B first,
// even blocks A first -> a CU's two resident blocks are mostly in different
// roles; MFMA windows overlap the neighbor's staging/barrier drains (m114).
// XCD-pinned u0 (perf heuristic only). Buffer schedule = verified 4-deep
// slab rotation (r8/r10/r11/r12/r14).
__global__ __launch_bounds__(256, 2) void step_kernel(
    int doA, int doB,
    // role A: layer 2 of step s-1
    const u16* __restrict__ Aa0, const u16* __restrict__ Aw0,
    const u16* __restrict__ Aa1, const u16* __restrict__ Aw1,
    const float* __restrict__ Abi, const float* __restrict__ Abh,
    float* __restrict__ Acbuf, u16* __restrict__ Aouth, int Afirst, int Ansrc,
    // role B: layer 1 of step s (x via pre-packed stride-64 pair)
    const u16* __restrict__ Ba0, const u16* __restrict__ Bw0,
    const u16* __restrict__ Bxp, const u16* __restrict__ Bwxp,
    const float* __restrict__ Bbi, const float* __restrict__ Bbh,
    float* __restrict__ Bcbuf, u16* __restrict__ Bouth, int Bfirst, int Bnsrc,
    // role O: output linear of step s-2 (Ot < 0 => skip)
    const u16* __restrict__ Oh2, const u16* __restrict__ Wlin,
    const float* __restrict__ blin, float* __restrict__ outp, int Ot)
{
    __shared__ u16 lA[256 * 64];   // 32 KB: 256 batch rows x BK=64
    __shared__ u16 lB[128 * 64];   // 16 KB: 128 weight rows x BK=64
    const int bid = blockIdx.x;
    const int rb  = (bid >> 5) * 256;                        // batch-row block
    const int u0  = ((bid & 7) * 4 + ((bid >> 3) & 3)) * 32; // XCD-pinned tile
    const auto runA = [&]() {
        gate_body(lA, lB, rb, u0, Aa0, Aw0, Aa1, Aw1, nullptr, nullptr,
                  Abi, Abh, Acbuf, Aouth, Afirst, Ansrc);
    };
    const auto runB = [&]() {
        gate_body(lA, lB, rb, u0, Ba0, Bw0, nullptr, nullptr, Bxp, Bwxp,
                  Bbi, Bbh, Bcbuf, Bouth, Bfirst, Bnsrc);
    };
    if (bid & 1) { if (doB) runB(); if (doA) runA(); }
    else         { if (doA) runA(); if (doB) runB(); }
    if (Ot >= 0)
        out_body8(bid, Oh2, Wlin, blin, outp, Ot);
}

extern "C" void kernel_launch(void* const* d_in, const int* in_sizes, int n_in,
                              void* d_out, int out_size, void* d_ws, size_t ws_size,
                              hipStream_t stream)
{
    const float* x     = (const float*)d_in[0];
    const float* W_ih1 = (const float*)d_in[1];
    const float* W_hh1 = (const float*)d_in[2];
    const float* b_ih1 = (const float*)d_in[3];
    const float* b_hh1 = (const float*)d_in[4];
    const float* W_ih2 = (const float*)d_in[5];
    const float* W_hh2 = (const float*)d_in[6];
    const float* b_ih2 = (const float*)d_in[7];
    const float* b_hh2 = (const float*)d_in[8];
    const float* W_lin = (const float*)d_in[9];
    const float* b_lin = (const float*)d_in[10];
    float* out = (float*)d_out;
    char* ws = (char*)d_ws;
    const size_t MB = (size_t)1 << 20;

    // Workspace (~132 MB; no memset -- first=1 skips all reads of
    // uninitialized state at t=0). c1/c2 fp32; h1/h2: FOUR 8MB fp16 slabs
    // each (t&3); wlin16 = fp16 W_lin for the O-body.
    float* c1 = (float*)(ws);             // 16 MB (4096x1024 fp32)
    float* c2 = (float*)(ws + 16 * MB);   // 16 MB
    u16* h1[4] = { (u16*)(ws + 32 * MB), (u16*)(ws + 40 * MB),
                   (u16*)(ws + 48 * MB), (u16*)(ws + 56 * MB) };
    u16* h2[4] = { (u16*)(ws + 64 * MB), (u16*)(ws + 72 * MB),
                   (u16*)(ws + 80 * MB), (u16*)(ws + 88 * MB) };
    u16* w1h    = (u16*)(ws + 96 * MB);   // 8 MB each (4H x H fp16)
    u16* w2ih   = (u16*)(ws + 104 * MB);
    u16* w2hh   = (u16*)(ws + 112 * MB);
    u16* xpack  = (u16*)(ws + 120 * MB);  // 19*4096*64 fp16 = 9.97 MB
    u16* wxpack = (u16*)(ws + 130 * MB);  // 4096*64 fp16 = 0.5 MB
    u16* wlin16 = (u16*)(ws + 131 * MB);  // 17*1024 fp16 = 34 KB

    // Prolog (3 launches): fused weight+W_lin fp16 splits, x / W_ih1 packs.
    const int nWlin4 = INDIM * HID / 4;   // 4352 float4s
    const int nTot = 3 * NW4 + nWlin4;
    split4_kernel<<<(nTot + 255) / 256, 256, 0, stream>>>(
        W_hh1, w1h, W_ih2, w2ih, W_hh2, w2hh, W_lin, wlin16, nWlin4);
    pack_x_kernel<<<(TSTEPS * 4096 + 255) / 256, 256, 0, stream>>>(x, xpack);
    pack_wx_kernel<<<(4 * HID + 255) / 256, 256, 0, stream>>>(W_ih1, wxpack);

    // Software pipeline: C(s) = { L2(s-1) + L1(s) + OUT(s-2) }, s=0..TSTEPS+1.
    // Slabs: L1(t) reads h1[(t+3)&3], writes h1[t&3]; L2(t) reads h1[t&3],
    // h2[(t+3)&3], writes h2[t&3]; OUT(t) reads h2[t&3]. Intra-launch sets
    // disjoint; RAW >= 1 launch, WAR >= 3 launches (verified r8-r14).
    for (int s = 0; s <= TSTEPS + 1; ++s) {
        const int ta = s - 1, tb = s, to = s - 2;
        const int doA = (s >= 1 && s <= TSTEPS) ? 1 : 0;
        const int doB = (s <= TSTEPS - 1) ? 1 : 0;
        step_kernel<<<512, 256, 0, stream>>>(
            doA, doB,
            // A: L2(ta) = h1[ta&3]@w2ih + h2[(ta+3)&3]@w2hh -> h2[ta&3]
            h1[ta & 3], w2ih, h2[(ta + 3) & 3], w2hh, b_ih2, b_hh2,
            c2, h2[ta & 3], (ta == 0) ? 1 : 0, (ta == 0) ? 1 : 2,
            // B: L1(tb) = xpack(tb) + h1[(tb+3)&3]@w1h -> h1[tb&3]
            h1[(tb + 3) & 3], w1h,
            xpack + (size_t)(tb < 0 ? 0 : tb) * 4096 * 64, wxpack,
            b_ih1, b_hh1,
            c1, h1[tb & 3], (tb == 0) ? 1 : 0, (tb == 0) ? 0 : 1,
            // O: OUT(to) reads h2[to&3] (skipped when to < 0)
            h2[to & 3], wlin16, b_lin, out, to);
    }
    (void)in_sizes; (void)n_in; (void)out_size; (void)ws_size;
}